// Round 3
// baseline (424.854 us; speedup 1.0000x reference)
//
#include <hip/hip_runtime.h>

#define B_ 64
#define NN 1024
#define FF 512

typedef float  fx4 __attribute__((ext_vector_type(4)));
typedef int    ix4 __attribute__((ext_vector_type(4)));
typedef unsigned int   ux4i __attribute__((ext_vector_type(4)));
typedef unsigned short us4  __attribute__((ext_vector_type(4)));
typedef short  sx8 __attribute__((ext_vector_type(8)));

static __device__ __forceinline__ unsigned short f2bf(float f){
    union { float f; unsigned u; } v; v.f = f;
    unsigned r = v.u + 0x7FFFu + ((v.u >> 16) & 1u);   // RTNE
    return (unsigned short)(r >> 16);
}
static __device__ __forceinline__ float bf2f(unsigned short h){
    union { unsigned u; float f; } v; v.u = ((unsigned)h) << 16;
    return v.f;
}

// ---------------- u1 = x @ We1 via MFMA, write bf16 transposed [B][32][1024] ----
// We1^T staged in LDS bf16 [32 col][512 k], 1024B col stride, chunk^(col&7) swizzle.
__global__ __launch_bounds__(512) void k_xw1(
    const float* __restrict__ x, const float* __restrict__ We1,
    unsigned short* __restrict__ u1T){
    __shared__ unsigned short wls[32*512];     // 32 KB
    int tid = threadIdx.x;
    for (int i = tid; i < 32*512; i += 512){
        int col = i >> 9, k = i & 511;
        float v = (col < 30) ? We1[k*30 + col] : 0.f;
        wls[col*512 + ((((k >> 3) ^ (col & 7)) << 3) | (k & 7))] = f2bf(v);
    }
    __syncthreads();
    int w = tid >> 6, l = tid & 63;
    int lr = l & 15, kq = l >> 4;
    int b = blockIdx.y;
    int rowb = blockIdx.x*128 + w*16;          // stripe base within batch
    const float* xp = x + ((size_t)b*NN + rowb + lr)*FF + kq*8;
    fx4 acc0 = {0,0,0,0}, acc1 = {0,0,0,0};
    int c0 = lr, c1 = 16 + lr;
    #pragma unroll 4
    for (int kk = 0; kk < FF; kk += 32){
        fx4 v0 = *(const fx4*)(xp + kk);
        fx4 v1 = *(const fx4*)(xp + kk + 4);
        sx8 a;
        #pragma unroll
        for (int t = 0; t < 4; t++){ a[t] = (short)f2bf(v0[t]); a[4+t] = (short)f2bf(v1[t]); }
        int chunk = (kk >> 3) + kq;
        sx8 b0 = *(const sx8*)(wls + c0*512 + ((chunk ^ (c0 & 7)) << 3));
        sx8 b1 = *(const sx8*)(wls + c1*512 + ((chunk ^ (c1 & 7)) << 3));
        acc0 = __builtin_amdgcn_mfma_f32_16x16x32_bf16(a, b0, acc0, 0, 0, 0);
        acc1 = __builtin_amdgcn_mfma_f32_16x16x32_bf16(a, b1, acc1, 0, 0, 0);
    }
    int row0 = rowb + kq*4;
    us4 o0 = { f2bf(acc0[0]), f2bf(acc0[1]), f2bf(acc0[2]), f2bf(acc0[3]) };
    us4 o1 = { f2bf(acc1[0]), f2bf(acc1[1]), f2bf(acc1[2]), f2bf(acc1[3]) };
    *(us4*)(u1T + ((size_t)b*32 + c0)*NN + row0) = o0;
    *(us4*)(u1T + ((size_t)b*32 + c1)*NN + row0) = o1;
}

// ---------------- out = act(adj @ U + bias), MFMA bf16 ----------------
// CVT: A read from f32 adj, converted in-register, bf16 fragment stored to adjb.
// RM : output written row-major [B][N][32] (for k_dec) instead of [B][32][N].
template<int CVT, int RM>
__global__ __launch_bounds__(256) void k_adjmm(
    const float* __restrict__ adjf,
    const unsigned short* __restrict__ adjb_in,
    unsigned short* __restrict__ adjb_out,
    const unsigned short* __restrict__ uT,
    const float* __restrict__ bias, int biasN, int relu,
    unsigned short* __restrict__ outT){
    __shared__ unsigned short uts[32*NN];  // 64 KB, XOR-swizzled
    int tid = threadIdx.x;
    int rt = blockIdx.x, b = blockIdx.y;
    const ux4i* src = (const ux4i*)(uT + (size_t)b*32*NN);
    #pragma unroll
    for (int i = 0; i < 16; i++){
        int j = tid + i*256;               // 16B-chunk index, c = j>>7
        int c = j >> 7;
        ux4i v = src[j];
        int dst = (j*16) ^ ((c & 7) << 4);
        *(ux4i*)((char*)uts + dst) = v;
    }
    __syncthreads();
    int w = tid >> 6, l = tid & 63;
    int lr = l & 15, lk = (l >> 4) * 8;
    size_t aoff = (size_t)b*NN*NN + (size_t)(rt*128 + w*32 + lr)*NN + lk;
    int c0 = lr, c1 = 16 + lr;
    fx4 acc00 = {0,0,0,0}, acc01 = {0,0,0,0}, acc10 = {0,0,0,0}, acc11 = {0,0,0,0};
    #pragma unroll 4
    for (int kk = 0; kk < NN; kk += 32){
        sx8 a0, a1;
        if (CVT){
            fx4 v00 = *(const fx4*)(adjf + aoff + kk);
            fx4 v01 = *(const fx4*)(adjf + aoff + kk + 4);
            fx4 v10 = *(const fx4*)(adjf + aoff + 16*NN + kk);
            fx4 v11 = *(const fx4*)(adjf + aoff + 16*NN + kk + 4);
            #pragma unroll
            for (int t = 0; t < 4; t++){
                a0[t] = (short)f2bf(v00[t]); a0[4+t] = (short)f2bf(v01[t]);
                a1[t] = (short)f2bf(v10[t]); a1[4+t] = (short)f2bf(v11[t]);
            }
            *(sx8*)(adjb_out + aoff + kk) = a0;
            *(sx8*)(adjb_out + aoff + 16*NN + kk) = a1;
        } else {
            a0 = *(const sx8*)(adjb_in + aoff + kk);
            a1 = *(const sx8*)(adjb_in + aoff + 16*NN + kk);
        }
        int kb = (kk + lk) * 2;
        sx8 b0 = *(const sx8*)((const char*)uts + ((c0*2048 + kb) ^ ((c0 & 7) << 4)));
        sx8 b1 = *(const sx8*)((const char*)uts + ((c1*2048 + kb) ^ ((c1 & 7) << 4)));
        acc00 = __builtin_amdgcn_mfma_f32_16x16x32_bf16(a0, b0, acc00, 0, 0, 0);
        acc01 = __builtin_amdgcn_mfma_f32_16x16x32_bf16(a0, b1, acc01, 0, 0, 0);
        acc10 = __builtin_amdgcn_mfma_f32_16x16x32_bf16(a1, b0, acc10, 0, 0, 0);
        acc11 = __builtin_amdgcn_mfma_f32_16x16x32_bf16(a1, b1, acc11, 0, 0, 0);
    }
    float bias0 = 0.f, bias1 = 0.f;
    if (bias){
        if (c0 < biasN) bias0 = bias[c0];
        if (c1 < biasN) bias1 = bias[c1];
    }
    int lq = l >> 4;
    #pragma unroll
    for (int mt = 0; mt < 2; mt++){
        int row0 = rt*128 + w*32 + mt*16 + lq*4;
        fx4 am0 = mt ? acc10 : acc00;
        fx4 am1 = mt ? acc11 : acc01;
        #pragma unroll
        for (int ct = 0; ct < 2; ct++){
            fx4 a = ct ? am1 : am0;
            float bb = ct ? bias1 : bias0;
            int col = ct ? c1 : c0;
            us4 o;
            #pragma unroll
            for (int j = 0; j < 4; j++){
                float v = a[j] + bb;
                if (relu) v = fmaxf(v, 0.f);
                o[j] = f2bf(v);
            }
            if (RM){
                #pragma unroll
                for (int j = 0; j < 4; j++)
                    outT[((size_t)b*NN + row0 + j)*32 + col] = o[j];
            } else {
                *(us4*)(outT + ((size_t)b*32 + col)*NN + row0) = o;
            }
        }
    }
}

// ---------------- tiny per-row transform: out = act(in @ W + bias) ----------------
template<int JI, int CO, bool RELU>
__global__ __launch_bounds__(256) void k_tiny(
    const unsigned short* __restrict__ inT, const float* __restrict__ W,
    const float* __restrict__ bias, unsigned short* __restrict__ outT){
    int n = blockIdx.x*256 + threadIdx.x;
    int b = blockIdx.y;
    const unsigned short* ip = inT + (size_t)b*32*NN + n;
    float in[JI];
    #pragma unroll
    for (int j = 0; j < JI; j++) in[j] = bf2f(ip[j*NN]);
    float acc[CO];
    #pragma unroll
    for (int c = 0; c < CO; c++) acc[c] = bias ? bias[c] : 0.f;
    #pragma unroll
    for (int j = 0; j < JI; j++){
        #pragma unroll
        for (int c = 0; c < CO; c++) acc[c] += in[j] * W[j*CO + c];
    }
    unsigned short* op = outT + (size_t)b*32*NN + n;
    #pragma unroll
    for (int c = 0; c < 32; c++){
        float v = (c < CO) ? (RELU ? fmaxf(acc[c], 0.f) : acc[c]) : 0.f;
        op[c*NN] = f2bf(v);
    }
}

// ---------------- dec = v2 @ Wd2 + bd2 via MFMA ; epilogue fused -----------------
// v2R: [65536][32] bf16 row-major. Wd2^T in LDS bf16 [512 col][32 k], 80B stride.
__global__ __launch_bounds__(512) void k_dec(
    const unsigned short* __restrict__ v2R,
    const float* __restrict__ Wd2, const float* __restrict__ bd2,
    const int* __restrict__ masks, const float* __restrict__ noise,
    float* __restrict__ dec, float* __restrict__ sampled, float* __restrict__ part){
    __shared__ unsigned short wls[512*40];     // 40960 B (80 B per col)
    __shared__ float red[8];
    int tid = threadIdx.x;
    for (int i = tid; i < 512*32; i += 512){
        int col = i & 511, k = i >> 9;
        float v = (k < 30) ? Wd2[k*512 + col] : 0.f;
        wls[col*40 + k] = f2bf(v);
    }
    __syncthreads();
    int w = tid >> 6, l = tid & 63;
    int lr = l & 15, kq = l >> 4;
    int rb = blockIdx.x*128 + w*16;            // global row base of this stripe
    sx8 a = *(const sx8*)(v2R + (size_t)(rb + lr)*32 + kq*8);
    const float LPC = 2.9930844722234733f;     // -log(sigma) - 0.5*log(2*pi)
    // softmax tiles ct=0,1
    fx4 accS0 = {0,0,0,0}, accS1 = {0,0,0,0};
    {
        sx8 b0 = *(const sx8*)(wls + lr*40 + kq*8);
        sx8 b1 = *(const sx8*)(wls + (16 + lr)*40 + kq*8);
        accS0 = __builtin_amdgcn_mfma_f32_16x16x32_bf16(a, b0, accS0, 0, 0, 0);
        accS1 = __builtin_amdgcn_mfma_f32_16x16x32_bf16(a, b1, accS1, 0, 0, 0);
    }
    float bia0 = bd2[lr], bia1 = bd2[16 + lr];
    float d0s[4], d1s[4], act0[4], act1[4];
    #pragma unroll
    for (int j = 0; j < 4; j++){
        float u0 = accS0[j] + bia0, u1 = accS1[j] + bia1;
        d0s[j] = u0; d1s[j] = u1;
        float mx = fmaxf(u0, u1);
        mx = fmaxf(mx, __shfl_xor(mx, 1, 16));
        mx = fmaxf(mx, __shfl_xor(mx, 2, 16));
        mx = fmaxf(mx, __shfl_xor(mx, 4, 16));
        mx = fmaxf(mx, __shfl_xor(mx, 8, 16));
        float e0 = __expf(u0 - mx), e1 = __expf(u1 - mx);
        float s = e0 + e1;
        s += __shfl_xor(s, 1, 16);
        s += __shfl_xor(s, 2, 16);
        s += __shfl_xor(s, 4, 16);
        s += __shfl_xor(s, 8, 16);
        float inv = 1.f / s;
        act0[j] = e0*inv; act1[j] = e1*inv;
    }
    float lp = 0.f;
    #pragma unroll 4
    for (int ct = 0; ct < 32; ct++){
        float dv[4], av[4];
        if (ct < 2){
            #pragma unroll
            for (int j = 0; j < 4; j++){
                dv[j] = ct ? d1s[j] : d0s[j];
                av[j] = ct ? act1[j] : act0[j];
            }
        } else {
            int c = ct*16 + lr;
            sx8 bb = *(const sx8*)(wls + c*40 + kq*8);
            fx4 acc = {0,0,0,0};
            acc = __builtin_amdgcn_mfma_f32_16x16x32_bf16(a, bb, acc, 0, 0, 0);
            float bi = bd2[c];
            #pragma unroll
            for (int j = 0; j < 4; j++){
                dv[j] = acc[j] + bi;
                av[j] = 1.f / (1.f + __expf(-dv[j]));
            }
        }
        #pragma unroll
        for (int j = 0; j < 4; j++){
            size_t off = (size_t)(rb + kq*4 + j)*FF + ct*16 + lr;
            int   m = masks[off];
            float z = noise[off];
            dec[off] = dv[j];
            sampled[off] = av[j] + (float)m*(0.02f*z);
            lp = fmaf((float)m, LPC - 0.5f*z*z, lp);
        }
    }
    #pragma unroll
    for (int off = 32; off > 0; off >>= 1) lp += __shfl_xor(lp, off);
    if (l == 0) red[w] = lp;
    __syncthreads();
    if (tid == 0){
        float s = 0.f;
        #pragma unroll
        for (int i = 0; i < 8; i++) s += red[i];
        part[blockIdx.x] = s;
    }
}

// ---------------- final: logp[b] = sum of 8 block partials ----------------
__global__ void k_lp(const float* __restrict__ part, float* __restrict__ logp){
    int t = threadIdx.x;   // 64 threads, one per batch
    float s = 0.f;
    #pragma unroll
    for (int i = 0; i < 8; i++) s += part[t*8 + i];
    logp[t] = s;
}

extern "C" void kernel_launch(void* const* d_in, const int* in_sizes, int n_in,
                              void* d_out, int out_size, void* d_ws, size_t ws_size,
                              hipStream_t stream){
    const float* x     = (const float*)d_in[0];
    const float* adj   = (const float*)d_in[1];
    const int*   masks = (const int*)  d_in[2];
    const float* noise = (const float*)d_in[3];
    const float* We1   = (const float*)d_in[4];
    const float* be1   = (const float*)d_in[5];
    const float* We2   = (const float*)d_in[6];
    const float* be2   = (const float*)d_in[7];
    const float* Wd1   = (const float*)d_in[8];
    const float* bd1   = (const float*)d_in[9];
    const float* Wd2   = (const float*)d_in[10];
    const float* bd2   = (const float*)d_in[11];

    float* dec     = (float*)d_out;
    float* sampled = dec + (size_t)B_*NN*FF;
    float* logp    = sampled + (size_t)B_*NN*FF;
    // dec region (134,217,728 B) doubles as bf16-adj scratch until k_dec
    unsigned short* adjb = (unsigned short*)d_out;
    unsigned short* bufA = (unsigned short*)d_ws;              // 4 MB each
    unsigned short* bufB = bufA + (size_t)B_*32*NN;
    float* part = (float*)bufB;   // reused after h2 is consumed (512 floats)

    k_xw1<<<dim3(8, B_), 512, 0, stream>>>(x, We1, bufA);                              // u1
    k_adjmm<1,0><<<dim3(8, B_), 256, 0, stream>>>(adj, nullptr, adjb, bufA, be1, 30, 1, bufB); // h1 (+cvt)
    k_tiny<30,18,false><<<dim3(4, B_), 256, 0, stream>>>(bufB, We2, nullptr, bufA);    // u2
    k_adjmm<0,0><<<dim3(8, B_), 256, 0, stream>>>(nullptr, adjb, nullptr, bufA, be2, 18, 0, bufB); // enc
    k_adjmm<0,0><<<dim3(8, B_), 256, 0, stream>>>(nullptr, adjb, nullptr, bufB, nullptr, 0, 0, bufA); // v1
    k_tiny<18,30,true><<<dim3(4, B_), 256, 0, stream>>>(bufA, Wd1, bd1, bufB);         // h2
    k_adjmm<0,1><<<dim3(8, B_), 256, 0, stream>>>(nullptr, adjb, nullptr, bufB, nullptr, 0, 0, bufA); // v2 row-major
    k_dec<<<512, 512, 0, stream>>>(bufA, Wd2, bd2, masks, noise, dec, sampled, part);
    k_lp<<<1, 64, 0, stream>>>(part, logp);
}

// Round 4
// 377.261 us; speedup vs baseline: 1.1262x; 1.1262x over previous
//
#include <hip/hip_runtime.h>

#define B_ 64
#define NN 1024
#define FF 512

typedef float  fx4 __attribute__((ext_vector_type(4)));
typedef int    ix4 __attribute__((ext_vector_type(4)));
typedef unsigned int   ux4i __attribute__((ext_vector_type(4)));
typedef unsigned short us4  __attribute__((ext_vector_type(4)));
typedef short  sx8 __attribute__((ext_vector_type(8)));

static __device__ __forceinline__ unsigned short f2bf(float f){
    union { float f; unsigned u; } v; v.f = f;
    unsigned r = v.u + 0x7FFFu + ((v.u >> 16) & 1u);   // RTNE
    return (unsigned short)(r >> 16);
}
static __device__ __forceinline__ float bf2f(unsigned short h){
    union { unsigned u; float f; } v; v.u = ((unsigned)h) << 16;
    return v.f;
}

// ---------------- u1 = x @ We1 via MFMA, write bf16 transposed [B][32][1024] ----
__global__ __launch_bounds__(512) void k_xw1(
    const float* __restrict__ x, const float* __restrict__ We1,
    unsigned short* __restrict__ u1T){
    __shared__ unsigned short wls[32*512];     // 32 KB
    int tid = threadIdx.x;
    for (int i = tid; i < 32*512; i += 512){
        int col = i >> 9, k = i & 511;
        float v = (col < 30) ? We1[k*30 + col] : 0.f;
        wls[col*512 + ((((k >> 3) ^ (col & 7)) << 3) | (k & 7))] = f2bf(v);
    }
    __syncthreads();
    int w = tid >> 6, l = tid & 63;
    int lr = l & 15, kq = l >> 4;
    int b = blockIdx.y;
    int rowb = blockIdx.x*128 + w*16;          // stripe base within batch
    const float* xp = x + ((size_t)b*NN + rowb + lr)*FF + kq*8;
    fx4 acc0 = {0,0,0,0}, acc1 = {0,0,0,0};
    int c0 = lr, c1 = 16 + lr;
    #pragma unroll 4
    for (int kk = 0; kk < FF; kk += 32){
        fx4 v0 = *(const fx4*)(xp + kk);
        fx4 v1 = *(const fx4*)(xp + kk + 4);
        sx8 a;
        #pragma unroll
        for (int t = 0; t < 4; t++){ a[t] = (short)f2bf(v0[t]); a[4+t] = (short)f2bf(v1[t]); }
        int chunk = (kk >> 3) + kq;
        sx8 b0 = *(const sx8*)(wls + c0*512 + ((chunk ^ (c0 & 7)) << 3));
        sx8 b1 = *(const sx8*)(wls + c1*512 + ((chunk ^ (c1 & 7)) << 3));
        acc0 = __builtin_amdgcn_mfma_f32_16x16x32_bf16(a, b0, acc0, 0, 0, 0);
        acc1 = __builtin_amdgcn_mfma_f32_16x16x32_bf16(a, b1, acc1, 0, 0, 0);
    }
    int row0 = rowb + kq*4;
    us4 o0 = { f2bf(acc0[0]), f2bf(acc0[1]), f2bf(acc0[2]), f2bf(acc0[3]) };
    us4 o1 = { f2bf(acc1[0]), f2bf(acc1[1]), f2bf(acc1[2]), f2bf(acc1[3]) };
    *(us4*)(u1T + ((size_t)b*32 + c0)*NN + row0) = o0;
    *(us4*)(u1T + ((size_t)b*32 + c1)*NN + row0) = o1;
}

// ---------------- out = act(adj @ U + bias), MFMA bf16 ----------------
template<int CVT, int RM>
__global__ __launch_bounds__(256) void k_adjmm(
    const float* __restrict__ adjf,
    const unsigned short* __restrict__ adjb_in,
    unsigned short* __restrict__ adjb_out,
    const unsigned short* __restrict__ uT,
    const float* __restrict__ bias, int biasN, int relu,
    unsigned short* __restrict__ outT){
    __shared__ unsigned short uts[32*NN];  // 64 KB, XOR-swizzled
    int tid = threadIdx.x;
    int rt = blockIdx.x, b = blockIdx.y;
    const ux4i* src = (const ux4i*)(uT + (size_t)b*32*NN);
    #pragma unroll
    for (int i = 0; i < 16; i++){
        int j = tid + i*256;               // 16B-chunk index, c = j>>7
        int c = j >> 7;
        ux4i v = src[j];
        int dst = (j*16) ^ ((c & 7) << 4);
        *(ux4i*)((char*)uts + dst) = v;
    }
    __syncthreads();
    int w = tid >> 6, l = tid & 63;
    int lr = l & 15, lk = (l >> 4) * 8;
    size_t aoff = (size_t)b*NN*NN + (size_t)(rt*128 + w*32 + lr)*NN + lk;
    int c0 = lr, c1 = 16 + lr;
    fx4 acc00 = {0,0,0,0}, acc01 = {0,0,0,0}, acc10 = {0,0,0,0}, acc11 = {0,0,0,0};
    #pragma unroll 4
    for (int kk = 0; kk < NN; kk += 32){
        sx8 a0, a1;
        if (CVT){
            fx4 v00 = *(const fx4*)(adjf + aoff + kk);
            fx4 v01 = *(const fx4*)(adjf + aoff + kk + 4);
            fx4 v10 = *(const fx4*)(adjf + aoff + 16*NN + kk);
            fx4 v11 = *(const fx4*)(adjf + aoff + 16*NN + kk + 4);
            #pragma unroll
            for (int t = 0; t < 4; t++){
                a0[t] = (short)f2bf(v00[t]); a0[4+t] = (short)f2bf(v01[t]);
                a1[t] = (short)f2bf(v10[t]); a1[4+t] = (short)f2bf(v11[t]);
            }
            *(sx8*)(adjb_out + aoff + kk) = a0;
            *(sx8*)(adjb_out + aoff + 16*NN + kk) = a1;
        } else {
            a0 = *(const sx8*)(adjb_in + aoff + kk);
            a1 = *(const sx8*)(adjb_in + aoff + 16*NN + kk);
        }
        int kb = (kk + lk) * 2;
        sx8 b0 = *(const sx8*)((const char*)uts + ((c0*2048 + kb) ^ ((c0 & 7) << 4)));
        sx8 b1 = *(const sx8*)((const char*)uts + ((c1*2048 + kb) ^ ((c1 & 7) << 4)));
        acc00 = __builtin_amdgcn_mfma_f32_16x16x32_bf16(a0, b0, acc00, 0, 0, 0);
        acc01 = __builtin_amdgcn_mfma_f32_16x16x32_bf16(a0, b1, acc01, 0, 0, 0);
        acc10 = __builtin_amdgcn_mfma_f32_16x16x32_bf16(a1, b0, acc10, 0, 0, 0);
        acc11 = __builtin_amdgcn_mfma_f32_16x16x32_bf16(a1, b1, acc11, 0, 0, 0);
    }
    float bias0 = 0.f, bias1 = 0.f;
    if (bias){
        if (c0 < biasN) bias0 = bias[c0];
        if (c1 < biasN) bias1 = bias[c1];
    }
    int lq = l >> 4;
    #pragma unroll
    for (int mt = 0; mt < 2; mt++){
        int row0 = rt*128 + w*32 + mt*16 + lq*4;
        fx4 am0 = mt ? acc10 : acc00;
        fx4 am1 = mt ? acc11 : acc01;
        #pragma unroll
        for (int ct = 0; ct < 2; ct++){
            fx4 a = ct ? am1 : am0;
            float bb = ct ? bias1 : bias0;
            int col = ct ? c1 : c0;
            us4 o;
            #pragma unroll
            for (int j = 0; j < 4; j++){
                float v = a[j] + bb;
                if (relu) v = fmaxf(v, 0.f);
                o[j] = f2bf(v);
            }
            if (RM){
                #pragma unroll
                for (int j = 0; j < 4; j++)
                    outT[((size_t)b*NN + row0 + j)*32 + col] = o[j];
            } else {
                *(us4*)(outT + ((size_t)b*32 + col)*NN + row0) = o;
            }
        }
    }
}

// ---------------- tiny per-row transform: out = act(in @ W + bias) ----------------
template<int JI, int CO, bool RELU>
__global__ __launch_bounds__(256) void k_tiny(
    const unsigned short* __restrict__ inT, const float* __restrict__ W,
    const float* __restrict__ bias, unsigned short* __restrict__ outT){
    int n = blockIdx.x*256 + threadIdx.x;
    int b = blockIdx.y;
    const unsigned short* ip = inT + (size_t)b*32*NN + n;
    float in[JI];
    #pragma unroll
    for (int j = 0; j < JI; j++) in[j] = bf2f(ip[j*NN]);
    float acc[CO];
    #pragma unroll
    for (int c = 0; c < CO; c++) acc[c] = bias ? bias[c] : 0.f;
    #pragma unroll
    for (int j = 0; j < JI; j++){
        #pragma unroll
        for (int c = 0; c < CO; c++) acc[c] += in[j] * W[j*CO + c];
    }
    unsigned short* op = outT + (size_t)b*32*NN + n;
    #pragma unroll
    for (int c = 0; c < 32; c++){
        float v = (c < CO) ? (RELU ? fmaxf(acc[c], 0.f) : acc[c]) : 0.f;
        op[c*NN] = f2bf(v);
    }
}

// ---------------- dec = v2 @ Wd2 + bd2 via MFMA ; LDS bounce ; coalesced stream --
// v2R: [65536][32] bf16 row-major. Wd2^T in LDS bf16 [512 col][32 k], 80B stride.
// Per 16-row stripe: MFMA -> dls[16][516] f32 -> barrier -> 1 wave streams 1 row
// (lane l owns 8 contiguous cols => 16B/lane fully-coalesced global traffic).
__global__ __launch_bounds__(512, 4) void k_dec(
    const unsigned short* __restrict__ v2R,
    const float* __restrict__ Wd2, const float* __restrict__ bd2,
    const int* __restrict__ masks, const float* __restrict__ noise,
    float* __restrict__ dec, float* __restrict__ sampled, float* __restrict__ part){
    __shared__ unsigned short wls[512*40];     // 40960 B
    __shared__ float dls[16][516];             // 33024 B (pad 4 -> 2-way max)
    __shared__ float red[8];
    int tid = threadIdx.x;
    for (int i = tid; i < 512*32; i += 512){
        int col = i & 511, k = i >> 9;
        float v = (k < 30) ? Wd2[k*512 + col] : 0.f;
        wls[col*40 + k] = f2bf(v);
    }
    int w = tid >> 6, l = tid & 63;
    int lr = l & 15, kq = l >> 4;
    const float LPC = 2.9930844722234733f;     // -log(sigma) - 0.5*log(2*pi)
    float lpacc = 0.f;
    __syncthreads();
    #pragma unroll
    for (int it = 0; it < 4; it++){
        int rbase = blockIdx.x*64 + it*16;     // global row base of this stripe
        // ---- MFMA phase: d[16][512] into LDS ----
        sx8 a = *(const sx8*)(v2R + (size_t)(rbase + lr)*32 + kq*8);
        #pragma unroll
        for (int i = 0; i < 4; i++){
            int c = (w + 8*i)*16 + lr;
            sx8 bb = *(const sx8*)(wls + c*40 + kq*8);
            fx4 acc = {0,0,0,0};
            acc = __builtin_amdgcn_mfma_f32_16x16x32_bf16(a, bb, acc, 0, 0, 0);
            float bi = bd2[c];
            #pragma unroll
            for (int j = 0; j < 4; j++)
                dls[kq*4 + j][c] = acc[j] + bi;
        }
        __syncthreads();
        // ---- stream phase: wave w handles rows w and w+8 of the stripe ----
        #pragma unroll
        for (int s = 0; s < 2; s++){
            int rloc = w + 8*s;
            size_t off = (size_t)(rbase + rloc)*FF + l*8;
            fx4 d0 = *(const fx4*)&dls[rloc][l*8];
            fx4 d1 = *(const fx4*)&dls[rloc][l*8 + 4];
            ix4 m0 = *(const ix4*)(masks + off);
            ix4 m1 = *(const ix4*)(masks + off + 4);
            fx4 z0 = *(const fx4*)(noise + off);
            fx4 z1 = *(const fx4*)(noise + off + 4);
            float av[8];
            #pragma unroll
            for (int i = 0; i < 4; i++){
                av[i]   = 1.f/(1.f + __expf(-d0[i]));
                av[4+i] = 1.f/(1.f + __expf(-d1[i]));
            }
            if (l < 4){                        // cols 0..31 -> softmax
                float mx = d0[0];
                #pragma unroll
                for (int i = 1; i < 4; i++) mx = fmaxf(mx, d0[i]);
                #pragma unroll
                for (int i = 0; i < 4; i++) mx = fmaxf(mx, d1[i]);
                mx = fmaxf(mx, __shfl_xor(mx, 1, 4));
                mx = fmaxf(mx, __shfl_xor(mx, 2, 4));
                float e[8], ss = 0.f;
                #pragma unroll
                for (int i = 0; i < 4; i++){ e[i] = __expf(d0[i] - mx); ss += e[i]; }
                #pragma unroll
                for (int i = 0; i < 4; i++){ e[4+i] = __expf(d1[i] - mx); ss += e[4+i]; }
                ss += __shfl_xor(ss, 1, 4);
                ss += __shfl_xor(ss, 2, 4);
                float inv = 1.f / ss;
                #pragma unroll
                for (int i = 0; i < 8; i++) av[i] = e[i]*inv;
            }
            *(fx4*)(dec + off)     = d0;
            *(fx4*)(dec + off + 4) = d1;
            fx4 sm0, sm1;
            #pragma unroll
            for (int i = 0; i < 4; i++){
                float mi0 = (float)m0[i], zi0 = z0[i];
                float mi1 = (float)m1[i], zi1 = z1[i];
                sm0[i] = av[i]   + mi0*(0.02f*zi0);
                sm1[i] = av[4+i] + mi1*(0.02f*zi1);
                lpacc = fmaf(mi0, LPC - 0.5f*zi0*zi0, lpacc);
                lpacc = fmaf(mi1, LPC - 0.5f*zi1*zi1, lpacc);
            }
            *(fx4*)(sampled + off)     = sm0;
            *(fx4*)(sampled + off + 4) = sm1;
        }
        __syncthreads();
    }
    #pragma unroll
    for (int off = 32; off > 0; off >>= 1) lpacc += __shfl_xor(lpacc, off);
    if (l == 0) red[w] = lpacc;
    __syncthreads();
    if (tid == 0){
        float s = 0.f;
        #pragma unroll
        for (int i = 0; i < 8; i++) s += red[i];
        part[blockIdx.x] = s;
    }
}

// ---------------- final: logp[b] = sum of 16 block partials ----------------
__global__ void k_lp(const float* __restrict__ part, float* __restrict__ logp){
    int t = threadIdx.x;   // 64 threads, one per batch
    float s = 0.f;
    #pragma unroll
    for (int i = 0; i < 16; i++) s += part[t*16 + i];
    logp[t] = s;
}

extern "C" void kernel_launch(void* const* d_in, const int* in_sizes, int n_in,
                              void* d_out, int out_size, void* d_ws, size_t ws_size,
                              hipStream_t stream){
    const float* x     = (const float*)d_in[0];
    const float* adj   = (const float*)d_in[1];
    const int*   masks = (const int*)  d_in[2];
    const float* noise = (const float*)d_in[3];
    const float* We1   = (const float*)d_in[4];
    const float* be1   = (const float*)d_in[5];
    const float* We2   = (const float*)d_in[6];
    const float* be2   = (const float*)d_in[7];
    const float* Wd1   = (const float*)d_in[8];
    const float* bd1   = (const float*)d_in[9];
    const float* Wd2   = (const float*)d_in[10];
    const float* bd2   = (const float*)d_in[11];

    float* dec     = (float*)d_out;
    float* sampled = dec + (size_t)B_*NN*FF;
    float* logp    = sampled + (size_t)B_*NN*FF;
    // dec region (134,217,728 B) doubles as bf16-adj scratch until k_dec
    unsigned short* adjb = (unsigned short*)d_out;
    unsigned short* bufA = (unsigned short*)d_ws;              // 4 MB each
    unsigned short* bufB = bufA + (size_t)B_*32*NN;
    float* part = (float*)bufB;   // reused after h2 is consumed (1024 floats)

    k_xw1<<<dim3(8, B_), 512, 0, stream>>>(x, We1, bufA);                              // u1
    k_adjmm<1,0><<<dim3(8, B_), 256, 0, stream>>>(adj, nullptr, adjb, bufA, be1, 30, 1, bufB); // h1 (+cvt)
    k_tiny<30,18,false><<<dim3(4, B_), 256, 0, stream>>>(bufB, We2, nullptr, bufA);    // u2
    k_adjmm<0,0><<<dim3(8, B_), 256, 0, stream>>>(nullptr, adjb, nullptr, bufA, be2, 18, 0, bufB); // enc
    k_adjmm<0,0><<<dim3(8, B_), 256, 0, stream>>>(nullptr, adjb, nullptr, bufB, nullptr, 0, 0, bufA); // v1
    k_tiny<18,30,true><<<dim3(4, B_), 256, 0, stream>>>(bufA, Wd1, bd1, bufB);         // h2
    k_adjmm<0,1><<<dim3(8, B_), 256, 0, stream>>>(nullptr, adjb, nullptr, bufB, nullptr, 0, 0, bufA); // v2 row-major
    k_dec<<<1024, 512, 0, stream>>>(bufA, Wd2, bd2, masks, noise, dec, sampled, part);
    k_lp<<<1, 64, 0, stream>>>(part, logp);
}

// Round 5
// 349.861 us; speedup vs baseline: 1.2144x; 1.0783x over previous
//
#include <hip/hip_runtime.h>

#define B_ 64
#define NN 1024
#define FF 512

typedef float  fx4 __attribute__((ext_vector_type(4)));
typedef float  fx2 __attribute__((ext_vector_type(2)));
typedef int    ix4 __attribute__((ext_vector_type(4)));
typedef unsigned int   ux4i __attribute__((ext_vector_type(4)));
typedef unsigned int   ux2i __attribute__((ext_vector_type(2)));
typedef unsigned short us4  __attribute__((ext_vector_type(4)));
typedef short  sx8 __attribute__((ext_vector_type(8)));

#define FP8_SCALE   16384.0f        // 2^14: adj*2^14 in [0,16] -> e4m3 normal range
#define INV_SCALE   6.103515625e-5f // 2^-14, folded into B operands (exact)

static __device__ __forceinline__ unsigned short f2bf(float f){
    union { float f; unsigned u; } v; v.f = f;
    unsigned r = v.u + 0x7FFFu + ((v.u >> 16) & 1u);   // RTNE
    return (unsigned short)(r >> 16);
}
static __device__ __forceinline__ float bf2f(unsigned short h){
    union { unsigned u; float f; } v; v.u = ((unsigned)h) << 16;
    return v.f;
}

// ---------------- u1 = x @ We1 via MFMA, write bf16 transposed [B][32][1024] ----
__global__ __launch_bounds__(512) void k_xw1(
    const float* __restrict__ x, const float* __restrict__ We1,
    unsigned short* __restrict__ u1T){
    __shared__ unsigned short wls[32*512];     // 32 KB
    int tid = threadIdx.x;
    for (int i = tid; i < 32*512; i += 512){
        int col = i >> 9, k = i & 511;
        float v = (col < 30) ? We1[k*30 + col] : 0.f;
        wls[col*512 + ((((k >> 3) ^ (col & 7)) << 3) | (k & 7))] = f2bf(v);
    }
    __syncthreads();
    int w = tid >> 6, l = tid & 63;
    int lr = l & 15, kq = l >> 4;
    int b = blockIdx.y;
    int rowb = blockIdx.x*128 + w*16;          // stripe base within batch
    const float* xp = x + ((size_t)b*NN + rowb + lr)*FF + kq*8;
    fx4 acc0 = {0,0,0,0}, acc1 = {0,0,0,0};
    int c0 = lr, c1 = 16 + lr;
    #pragma unroll 4
    for (int kk = 0; kk < FF; kk += 32){
        fx4 v0 = *(const fx4*)(xp + kk);
        fx4 v1 = *(const fx4*)(xp + kk + 4);
        sx8 a;
        #pragma unroll
        for (int t = 0; t < 4; t++){ a[t] = (short)f2bf(v0[t]); a[4+t] = (short)f2bf(v1[t]); }
        int chunk = (kk >> 3) + kq;
        sx8 b0 = *(const sx8*)(wls + c0*512 + ((chunk ^ (c0 & 7)) << 3));
        sx8 b1 = *(const sx8*)(wls + c1*512 + ((chunk ^ (c1 & 7)) << 3));
        acc0 = __builtin_amdgcn_mfma_f32_16x16x32_bf16(a, b0, acc0, 0, 0, 0);
        acc1 = __builtin_amdgcn_mfma_f32_16x16x32_bf16(a, b1, acc1, 0, 0, 0);
    }
    int row0 = rowb + kq*4;
    us4 o0 = { f2bf(acc0[0]), f2bf(acc0[1]), f2bf(acc0[2]), f2bf(acc0[3]) };
    us4 o1 = { f2bf(acc1[0]), f2bf(acc1[1]), f2bf(acc1[2]), f2bf(acc1[3]) };
    *(us4*)(u1T + ((size_t)b*32 + c0)*NN + row0) = o0;
    *(us4*)(u1T + ((size_t)b*32 + c1)*NN + row0) = o1;
}

// ------- pass 1: h1 = relu(adj @ u1 + be1), adj f32 -> bf16 MFMA + fp8 store ----
__global__ __launch_bounds__(256) void k_cvt_h1(
    const float* __restrict__ adjf, unsigned char* __restrict__ adj8,
    const unsigned short* __restrict__ uT, const float* __restrict__ bias,
    unsigned short* __restrict__ outT){
    __shared__ unsigned short uts[32*NN];  // 64 KB, XOR-swizzled
    int tid = threadIdx.x;
    int rt = blockIdx.x, b = blockIdx.y;
    const ux4i* src = (const ux4i*)(uT + (size_t)b*32*NN);
    #pragma unroll
    for (int i = 0; i < 16; i++){
        int j = tid + i*256;
        int c = j >> 7;
        ux4i v = src[j];
        int dst = (j*16) ^ ((c & 7) << 4);
        *(ux4i*)((char*)uts + dst) = v;
    }
    __syncthreads();
    int w = tid >> 6, l = tid & 63;
    int lr = l & 15, lk = (l >> 4) * 8;
    size_t aoff = (size_t)b*NN*NN + (size_t)(rt*128 + w*32 + lr)*NN + lk;
    int c0 = lr, c1 = 16 + lr;
    fx4 acc00 = {0,0,0,0}, acc01 = {0,0,0,0}, acc10 = {0,0,0,0}, acc11 = {0,0,0,0};
    #pragma unroll 4
    for (int kk = 0; kk < NN; kk += 32){
        fx4 v00 = *(const fx4*)(adjf + aoff + kk);
        fx4 v01 = *(const fx4*)(adjf + aoff + kk + 4);
        fx4 v10 = *(const fx4*)(adjf + aoff + 16*NN + kk);
        fx4 v11 = *(const fx4*)(adjf + aoff + 16*NN + kk + 4);
        sx8 a0, a1;
        #pragma unroll
        for (int t = 0; t < 4; t++){
            a0[t] = (short)f2bf(v00[t]); a0[4+t] = (short)f2bf(v01[t]);
            a1[t] = (short)f2bf(v10[t]); a1[4+t] = (short)f2bf(v11[t]);
        }
        // fp8 e4m3 store of adj*2^14 (RNE via HW cvt)
        {
            const float S = FP8_SCALE;
            int d0 = __builtin_amdgcn_cvt_pk_fp8_f32(v00[0]*S, v00[1]*S, 0, false);
            d0     = __builtin_amdgcn_cvt_pk_fp8_f32(v00[2]*S, v00[3]*S, d0, true);
            int d1 = __builtin_amdgcn_cvt_pk_fp8_f32(v01[0]*S, v01[1]*S, 0, false);
            d1     = __builtin_amdgcn_cvt_pk_fp8_f32(v01[2]*S, v01[3]*S, d1, true);
            ux2i s0 = { (unsigned)d0, (unsigned)d1 };
            *(ux2i*)(adj8 + aoff + kk) = s0;
            int d2 = __builtin_amdgcn_cvt_pk_fp8_f32(v10[0]*S, v10[1]*S, 0, false);
            d2     = __builtin_amdgcn_cvt_pk_fp8_f32(v10[2]*S, v10[3]*S, d2, true);
            int d3 = __builtin_amdgcn_cvt_pk_fp8_f32(v11[0]*S, v11[1]*S, 0, false);
            d3     = __builtin_amdgcn_cvt_pk_fp8_f32(v11[2]*S, v11[3]*S, d3, true);
            ux2i s1 = { (unsigned)d2, (unsigned)d3 };
            *(ux2i*)(adj8 + aoff + 16*NN + kk) = s1;
        }
        int kb = (kk + lk) * 2;
        sx8 b0 = *(const sx8*)((const char*)uts + ((c0*2048 + kb) ^ ((c0 & 7) << 4)));
        sx8 b1 = *(const sx8*)((const char*)uts + ((c1*2048 + kb) ^ ((c1 & 7) << 4)));
        acc00 = __builtin_amdgcn_mfma_f32_16x16x32_bf16(a0, b0, acc00, 0, 0, 0);
        acc01 = __builtin_amdgcn_mfma_f32_16x16x32_bf16(a0, b1, acc01, 0, 0, 0);
        acc10 = __builtin_amdgcn_mfma_f32_16x16x32_bf16(a1, b0, acc10, 0, 0, 0);
        acc11 = __builtin_amdgcn_mfma_f32_16x16x32_bf16(a1, b1, acc11, 0, 0, 0);
    }
    float bias0 = (c0 < 30) ? bias[c0] : 0.f;
    float bias1 = 0.f;   // c1 = 16+lr < 30 always (lr<=15 -> c1<=31; cols 30,31 are pad)
    if (c1 < 30) bias1 = bias[c1];
    int lq = l >> 4;
    #pragma unroll
    for (int mt = 0; mt < 2; mt++){
        int row0 = rt*128 + w*32 + mt*16 + lq*4;
        fx4 am0 = mt ? acc10 : acc00;
        fx4 am1 = mt ? acc11 : acc01;
        #pragma unroll
        for (int ct = 0; ct < 2; ct++){
            fx4 a = ct ? am1 : am0;
            float bb = ct ? bias1 : bias0;
            int col = ct ? c1 : c0;
            us4 o;
            #pragma unroll
            for (int j = 0; j < 4; j++){
                float v = fmaxf(a[j] + bb, 0.f);   // relu
                o[j] = f2bf(v);
            }
            *(us4*)(outT + ((size_t)b*32 + col)*NN + row0) = o;
        }
    }
}

// ------- fp8 adj pass: out = (2^14*adj_q) @ U_scaled (+bias), oscale on write ----
// adj8: [B][1024][1024] fp8(e4m3, adj*2^14); uT pre-scaled by 2^-14 by producer.
template<int RM>
__global__ __launch_bounds__(256) void k_adjf8(
    const unsigned char* __restrict__ adj8,
    const unsigned short* __restrict__ uT,
    const float* __restrict__ bias, int biasN, float oscale,
    unsigned short* __restrict__ outT){
    __shared__ unsigned short uts[32*NN];  // 64 KB, XOR-swizzled
    int tid = threadIdx.x;
    int rt = blockIdx.x, b = blockIdx.y;
    const ux4i* src = (const ux4i*)(uT + (size_t)b*32*NN);
    #pragma unroll
    for (int i = 0; i < 16; i++){
        int j = tid + i*256;
        int c = j >> 7;
        ux4i v = src[j];
        int dst = (j*16) ^ ((c & 7) << 4);
        *(ux4i*)((char*)uts + dst) = v;
    }
    __syncthreads();
    int w = tid >> 6, l = tid & 63;
    int lr = l & 15, lk = (l >> 4) * 8;
    size_t aoff = (size_t)b*NN*NN + (size_t)(rt*128 + w*32 + lr)*NN + lk;
    int c0 = lr, c1 = 16 + lr;
    fx4 acc00 = {0,0,0,0}, acc01 = {0,0,0,0}, acc10 = {0,0,0,0}, acc11 = {0,0,0,0};
    #pragma unroll 4
    for (int kk = 0; kk < NN; kk += 32){
        ux2i q0 = *(const ux2i*)(adj8 + aoff + kk);
        ux2i q1 = *(const ux2i*)(adj8 + aoff + 16*NN + kk);
        fx2 f0 = __builtin_amdgcn_cvt_pk_f32_fp8((int)q0[0], false);
        fx2 f1 = __builtin_amdgcn_cvt_pk_f32_fp8((int)q0[0], true);
        fx2 f2 = __builtin_amdgcn_cvt_pk_f32_fp8((int)q0[1], false);
        fx2 f3 = __builtin_amdgcn_cvt_pk_f32_fp8((int)q0[1], true);
        fx2 g0 = __builtin_amdgcn_cvt_pk_f32_fp8((int)q1[0], false);
        fx2 g1 = __builtin_amdgcn_cvt_pk_f32_fp8((int)q1[0], true);
        fx2 g2 = __builtin_amdgcn_cvt_pk_f32_fp8((int)q1[1], false);
        fx2 g3 = __builtin_amdgcn_cvt_pk_f32_fp8((int)q1[1], true);
        sx8 a0, a1;
        a0[0]=(short)f2bf(f0[0]); a0[1]=(short)f2bf(f0[1]);
        a0[2]=(short)f2bf(f1[0]); a0[3]=(short)f2bf(f1[1]);
        a0[4]=(short)f2bf(f2[0]); a0[5]=(short)f2bf(f2[1]);
        a0[6]=(short)f2bf(f3[0]); a0[7]=(short)f2bf(f3[1]);
        a1[0]=(short)f2bf(g0[0]); a1[1]=(short)f2bf(g0[1]);
        a1[2]=(short)f2bf(g1[0]); a1[3]=(short)f2bf(g1[1]);
        a1[4]=(short)f2bf(g2[0]); a1[5]=(short)f2bf(g2[1]);
        a1[6]=(short)f2bf(g3[0]); a1[7]=(short)f2bf(g3[1]);
        int kb = (kk + lk) * 2;
        sx8 b0 = *(const sx8*)((const char*)uts + ((c0*2048 + kb) ^ ((c0 & 7) << 4)));
        sx8 b1 = *(const sx8*)((const char*)uts + ((c1*2048 + kb) ^ ((c1 & 7) << 4)));
        acc00 = __builtin_amdgcn_mfma_f32_16x16x32_bf16(a0, b0, acc00, 0, 0, 0);
        acc01 = __builtin_amdgcn_mfma_f32_16x16x32_bf16(a0, b1, acc01, 0, 0, 0);
        acc10 = __builtin_amdgcn_mfma_f32_16x16x32_bf16(a1, b0, acc10, 0, 0, 0);
        acc11 = __builtin_amdgcn_mfma_f32_16x16x32_bf16(a1, b1, acc11, 0, 0, 0);
    }
    float bias0 = 0.f, bias1 = 0.f;
    if (bias){
        if (c0 < biasN) bias0 = bias[c0];
        if (c1 < biasN) bias1 = bias[c1];
    }
    int lq = l >> 4;
    #pragma unroll
    for (int mt = 0; mt < 2; mt++){
        int row0 = rt*128 + w*32 + mt*16 + lq*4;
        fx4 am0 = mt ? acc10 : acc00;
        fx4 am1 = mt ? acc11 : acc01;
        #pragma unroll
        for (int ct = 0; ct < 2; ct++){
            fx4 a = ct ? am1 : am0;
            float bb = ct ? bias1 : bias0;
            int col = ct ? c1 : c0;
            us4 o;
            #pragma unroll
            for (int j = 0; j < 4; j++){
                float v = (a[j] + bb) * oscale;
                o[j] = f2bf(v);
            }
            if (RM){
                #pragma unroll
                for (int j = 0; j < 4; j++)
                    outT[((size_t)b*NN + row0 + j)*32 + col] = o[j];
            } else {
                *(us4*)(outT + ((size_t)b*32 + col)*NN + row0) = o;
            }
        }
    }
}

// ---------------- tiny per-row transform: out = act(in @ W + bias) * oscale ------
template<int JI, int CO, bool RELU>
__global__ __launch_bounds__(256) void k_tiny(
    const unsigned short* __restrict__ inT, const float* __restrict__ W,
    const float* __restrict__ bias, float oscale,
    unsigned short* __restrict__ outT){
    int n = blockIdx.x*256 + threadIdx.x;
    int b = blockIdx.y;
    const unsigned short* ip = inT + (size_t)b*32*NN + n;
    float in[JI];
    #pragma unroll
    for (int j = 0; j < JI; j++) in[j] = bf2f(ip[j*NN]);
    float acc[CO];
    #pragma unroll
    for (int c = 0; c < CO; c++) acc[c] = bias ? bias[c] : 0.f;
    #pragma unroll
    for (int j = 0; j < JI; j++){
        #pragma unroll
        for (int c = 0; c < CO; c++) acc[c] += in[j] * W[j*CO + c];
    }
    unsigned short* op = outT + (size_t)b*32*NN + n;
    #pragma unroll
    for (int c = 0; c < 32; c++){
        float v = (c < CO) ? (RELU ? fmaxf(acc[c], 0.f) : acc[c]) * oscale : 0.f;
        op[c*NN] = f2bf(v);
    }
}

// ---------------- dec = v2 @ Wd2 + bd2 via MFMA ; LDS bounce ; coalesced stream --
__global__ __launch_bounds__(512, 4) void k_dec(
    const unsigned short* __restrict__ v2R,
    const float* __restrict__ Wd2, const float* __restrict__ bd2,
    const int* __restrict__ masks, const float* __restrict__ noise,
    float* __restrict__ dec, float* __restrict__ sampled, float* __restrict__ part){
    __shared__ unsigned short wls[512*40];     // 40960 B
    __shared__ float dls[16][516];             // 33024 B
    __shared__ float red[8];
    int tid = threadIdx.x;
    for (int i = tid; i < 512*32; i += 512){
        int col = i & 511, k = i >> 9;
        float v = (k < 30) ? Wd2[k*512 + col] : 0.f;
        wls[col*40 + k] = f2bf(v);
    }
    int w = tid >> 6, l = tid & 63;
    int lr = l & 15, kq = l >> 4;
    const float LPC = 2.9930844722234733f;     // -log(sigma) - 0.5*log(2*pi)
    float lpacc = 0.f;
    __syncthreads();
    #pragma unroll
    for (int it = 0; it < 4; it++){
        int rbase = blockIdx.x*64 + it*16;
        sx8 a = *(const sx8*)(v2R + (size_t)(rbase + lr)*32 + kq*8);
        #pragma unroll
        for (int i = 0; i < 4; i++){
            int c = (w + 8*i)*16 + lr;
            sx8 bb = *(const sx8*)(wls + c*40 + kq*8);
            fx4 acc = {0,0,0,0};
            acc = __builtin_amdgcn_mfma_f32_16x16x32_bf16(a, bb, acc, 0, 0, 0);
            float bi = bd2[c];
            #pragma unroll
            for (int j = 0; j < 4; j++)
                dls[kq*4 + j][c] = acc[j] + bi;
        }
        __syncthreads();
        #pragma unroll
        for (int s = 0; s < 2; s++){
            int rloc = w + 8*s;
            size_t off = (size_t)(rbase + rloc)*FF + l*8;
            fx4 d0 = *(const fx4*)&dls[rloc][l*8];
            fx4 d1 = *(const fx4*)&dls[rloc][l*8 + 4];
            ix4 m0 = *(const ix4*)(masks + off);
            ix4 m1 = *(const ix4*)(masks + off + 4);
            fx4 z0 = *(const fx4*)(noise + off);
            fx4 z1 = *(const fx4*)(noise + off + 4);
            float av[8];
            #pragma unroll
            for (int i = 0; i < 4; i++){
                av[i]   = 1.f/(1.f + __expf(-d0[i]));
                av[4+i] = 1.f/(1.f + __expf(-d1[i]));
            }
            if (l < 4){                        // cols 0..31 -> softmax
                float mx = d0[0];
                #pragma unroll
                for (int i = 1; i < 4; i++) mx = fmaxf(mx, d0[i]);
                #pragma unroll
                for (int i = 0; i < 4; i++) mx = fmaxf(mx, d1[i]);
                mx = fmaxf(mx, __shfl_xor(mx, 1, 4));
                mx = fmaxf(mx, __shfl_xor(mx, 2, 4));
                float e[8], ss = 0.f;
                #pragma unroll
                for (int i = 0; i < 4; i++){ e[i] = __expf(d0[i] - mx); ss += e[i]; }
                #pragma unroll
                for (int i = 0; i < 4; i++){ e[4+i] = __expf(d1[i] - mx); ss += e[4+i]; }
                ss += __shfl_xor(ss, 1, 4);
                ss += __shfl_xor(ss, 2, 4);
                float inv = 1.f / ss;
                #pragma unroll
                for (int i = 0; i < 8; i++) av[i] = e[i]*inv;
            }
            *(fx4*)(dec + off)     = d0;
            *(fx4*)(dec + off + 4) = d1;
            fx4 sm0, sm1;
            #pragma unroll
            for (int i = 0; i < 4; i++){
                float mi0 = (float)m0[i], zi0 = z0[i];
                float mi1 = (float)m1[i], zi1 = z1[i];
                sm0[i] = av[i]   + mi0*(0.02f*zi0);
                sm1[i] = av[4+i] + mi1*(0.02f*zi1);
                lpacc = fmaf(mi0, LPC - 0.5f*zi0*zi0, lpacc);
                lpacc = fmaf(mi1, LPC - 0.5f*zi1*zi1, lpacc);
            }
            *(fx4*)(sampled + off)     = sm0;
            *(fx4*)(sampled + off + 4) = sm1;
        }
        __syncthreads();
    }
    #pragma unroll
    for (int off = 32; off > 0; off >>= 1) lpacc += __shfl_xor(lpacc, off);
    if (l == 0) red[w] = lpacc;
    __syncthreads();
    if (tid == 0){
        float s = 0.f;
        #pragma unroll
        for (int i = 0; i < 8; i++) s += red[i];
        part[blockIdx.x] = s;
    }
}

// ---------------- final: logp[b] = sum of 16 block partials ----------------
__global__ void k_lp(const float* __restrict__ part, float* __restrict__ logp){
    int t = threadIdx.x;   // 64 threads, one per batch
    float s = 0.f;
    #pragma unroll
    for (int i = 0; i < 16; i++) s += part[t*16 + i];
    logp[t] = s;
}

extern "C" void kernel_launch(void* const* d_in, const int* in_sizes, int n_in,
                              void* d_out, int out_size, void* d_ws, size_t ws_size,
                              hipStream_t stream){
    const float* x     = (const float*)d_in[0];
    const float* adj   = (const float*)d_in[1];
    const int*   masks = (const int*)  d_in[2];
    const float* noise = (const float*)d_in[3];
    const float* We1   = (const float*)d_in[4];
    const float* be1   = (const float*)d_in[5];
    const float* We2   = (const float*)d_in[6];
    const float* be2   = (const float*)d_in[7];
    const float* Wd1   = (const float*)d_in[8];
    const float* bd1   = (const float*)d_in[9];
    const float* Wd2   = (const float*)d_in[10];
    const float* bd2   = (const float*)d_in[11];

    float* dec     = (float*)d_out;
    float* sampled = dec + (size_t)B_*NN*FF;
    float* logp    = sampled + (size_t)B_*NN*FF;
    // dec region (134,217,728 B) doubles as fp8-adj scratch (67 MB) until k_dec
    unsigned char* adj8 = (unsigned char*)d_out;
    unsigned short* bufA = (unsigned short*)d_ws;              // 4 MB each
    unsigned short* bufB = bufA + (size_t)B_*32*NN;
    float* part = (float*)bufB;   // reused after h2 is consumed (1024 floats)

    k_xw1<<<dim3(8, B_), 512, 0, stream>>>(x, We1, bufA);                                   // u1
    k_cvt_h1<<<dim3(8, B_), 256, 0, stream>>>(adj, adj8, bufA, be1, bufB);                  // h1 (+fp8 cvt)
    k_tiny<30,18,false><<<dim3(4, B_), 256, 0, stream>>>(bufB, We2, nullptr, INV_SCALE, bufA); // u2 (scaled)
    k_adjf8<0><<<dim3(8, B_), 256, 0, stream>>>(adj8, bufA, be2, 18, INV_SCALE, bufB);      // enc (scaled)
    k_adjf8<0><<<dim3(8, B_), 256, 0, stream>>>(adj8, bufB, nullptr, 0, 1.0f, bufA);        // v1 (true)
    k_tiny<18,30,true><<<dim3(4, B_), 256, 0, stream>>>(bufA, Wd1, bd1, INV_SCALE, bufB);   // h2 (scaled)
    k_adjf8<1><<<dim3(8, B_), 256, 0, stream>>>(adj8, bufB, nullptr, 0, 1.0f, bufA);        // v2 row-major
    k_dec<<<1024, 512, 0, stream>>>(bufA, Wd2, bd2, masks, noise, dec, sampled, part);
    k_lp<<<1, 64, 0, stream>>>(part, logp);
}